// Round 10
// baseline (267.737 us; speedup 1.0000x reference)
//
#include <hip/hip_runtime.h>
#include <math.h>

#define NV 10000
#define ND 300
#define NB 64
#define NL 128
#define CFv 5.0f
#define EPSV 1e-8f

// ws float-index layout (~46 MB used; ws >= 1.6 GB per harness fill)
#define WS_CTX   0        // 300 floats
#define WS_CN    300      // 1 float
#define WS_CNT   301      // 1 int (active-row count)
#define WS_A     320      // 10000 floats: CF*lam*cos
#define WS_B     10320    // 10000 floats: CF*(1-lam)*aff
#define WS_ROWS  20320    // 8192 ints (compacted, SORTED active row ids b*128+l)
#define WS_S     28512    // 8192 floats (unused now, kept for layout stability)
#define WS_CUM   36704    // 65 ints (per-batch prefix sums)
#define WS_WTG   36800    // bf16 WtG[304][10112] -> 1537024 floats
#define WS_SP    1573824  // f32 Spart[4][8192]
#define WS_U     1606592  // f32 U[4][8192][304]
#define UQSTRIDE 2490368  // 8192*304

#define QK    2496        // K-quarter base length (q3 = 2512)
#define WTGLD 10112
#define NTI   19          // 19 n-tiles of 16 cover 304
#define MT    32          // rows per block
#define MGMAX 256         // ceil(8192/32)

typedef __attribute__((ext_vector_type(8))) __bf16 bf16x8;
typedef __attribute__((ext_vector_type(4))) float f32x4;

static __device__ __forceinline__ unsigned short f2bf(float x) {
  union { float f; unsigned u; } v; v.f = x;
  unsigned r = v.u + 0x7fffu + ((v.u >> 16) & 1u);
  return (unsigned short)(r >> 16);
}

__global__ __launch_bounds__(256) void k_init(float* __restrict__ wsf) {
  int g = blockIdx.x * 256 + threadIdx.x;
  if (g < 302) wsf[g] = 0.f;
}

#define CSL 4
__global__ __launch_bounds__(320) void k_context(const int* __restrict__ clist,
                                                 const int* __restrict__ clen,
                                                 const float* __restrict__ embed,
                                                 float* __restrict__ wsf) {
  __shared__ int kl[NL];
  int b = blockIdx.x / CSL, sl = blockIdx.x % CSL;
  int d = threadIdx.x;
  int len = clen[b];
  if (d < NL) kl[d] = clist[b * NL + d];
  __syncthreads();
  if (d >= ND) return;
  float acc = 0.f;
  for (int l = sl; l < len; l += CSL)
    acc += embed[(long)kl[l] * ND + d];
  float dn = (float)(len > 0 ? len : 1);
  atomicAdd(&wsf[WS_CTX + d], acc * (1.0f / NB) / dn);
}

__global__ __launch_bounds__(320) void k_cn(float* __restrict__ wsf) {
  __shared__ float red[5];
  int t = threadIdx.x;
  float x = (t < ND) ? wsf[WS_CTX + t] : 0.f;
  float s = x * x;
  #pragma unroll
  for (int o = 32; o; o >>= 1) s += __shfl_xor(s, o);
  if ((t & 63) == 0) red[t >> 6] = s;
  __syncthreads();
  if (t == 0) {
    float tot = 0.f;
    #pragma unroll
    for (int i = 0; i < 5; ++i) tot += red[i];
    wsf[WS_CN] = sqrtf(tot);
  }
}

// per-concept |cos| then fused constants A = CF*lam*cos, B = CF*(1-lam)*aff
__global__ __launch_bounds__(256) void k_cos(const float* __restrict__ cw,
                                             const float* __restrict__ lam,
                                             const float* __restrict__ aff,
                                             float* __restrict__ wsf) {
  int wid = threadIdx.x >> 6, lane = threadIdx.x & 63;
  int v = blockIdx.x * 4 + wid;
  const float* row = cw + (long)v * ND;
  float dot = 0.f, rn2 = 0.f;
  for (int d = lane; d < ND; d += 64) {
    float w = row[d], c = wsf[WS_CTX + d];
    dot += w * c;
    rn2 += w * w;
  }
  #pragma unroll
  for (int o = 32; o; o >>= 1) { dot += __shfl_xor(dot, o); rn2 += __shfl_xor(rn2, o); }
  if (lane == 0) {
    float cn = wsf[WS_CN];
    float cosv = fabsf(dot) / fmaxf(cn * sqrtf(rn2), EPSV);
    float lv = lam[v];
    wsf[WS_A + v] = CFv * lv * cosv;
    wsf[WS_B + v] = CFv * (1.f - lv) * aff[v];
  }
}

// transpose concept_w -> bf16 WtG[304][WTGLD] in ws (zero-padded rows/cols)
__global__ __launch_bounds__(256) void k_wt(const float* __restrict__ cw, float* __restrict__ wsf) {
  __shared__ unsigned short T[304][68];
  int tid = threadIdx.x;
  int v0 = blockIdx.x * 64;
  for (int q = tid; q < 304 * 68 / 2; q += 256) ((unsigned*)&T[0][0])[q] = 0u;
  __syncthreads();
  const float4* cw4 = (const float4*)cw;
  for (int q = tid; q < 64 * 75; q += 256) {
    int r = q / 75, p = q - r * 75;
    int v = v0 + r;
    if (v < NV) {
      float4 w = cw4[(long)v * 75 + p];
      T[4 * p + 0][r] = f2bf(w.x);
      T[4 * p + 1][r] = f2bf(w.y);
      T[4 * p + 2][r] = f2bf(w.z);
      T[4 * p + 3][r] = f2bf(w.w);
    }
  }
  __syncthreads();
  unsigned short* wtg = (unsigned short*)(wsf + WS_WTG);
  for (int q = tid; q < 304 * 16; q += 256) {
    int n = q >> 4, rp = q & 15;
    *(ushort4*)&wtg[(long)n * WTGLD + v0 + 4 * rp] = *(const ushort4*)&T[n][4 * rp];
  }
}

// parallel compaction + cum store
__global__ __launch_bounds__(256) void k_compact(const int* __restrict__ clen, int* __restrict__ wsi) {
  __shared__ int cum[NB + 1];
  int tid = threadIdx.x;
  if (tid < 64) {
    int ln = clen[tid]; ln = min(max(ln, 0), NL);
    int s = ln;
    #pragma unroll
    for (int o = 1; o < 64; o <<= 1) {
      int t = __shfl_up(s, o);
      if (tid >= o) s += t;
    }
    cum[tid + 1] = s;
    if (tid == 0) cum[0] = 0;
    if (tid == 63) wsi[WS_CNT] = s;
  }
  __syncthreads();
  if (tid <= NB) wsi[WS_CUM + tid] = cum[tid];
  int t = blockIdx.x * 256 + tid;   // grid 32 covers 8192
  int b = t >> 7, l = t & 127;
  int len = cum[b + 1] - cum[b];
  if (l < len) wsi[WS_ROWS + cum[b] + l] = t;
}

// Fused GEMM + partial softmax-denominator. Block = (M-group mg: 32 rows) x
// (K-quarter q). Sweeps its quarter with persistent register acc, computes
// S_part from the same exp values, stores UNNORMALIZED U and Spart (owned,
// plain stores, no atomics). blockIdx&3=q so XCD x serves quarter x&3 (L2-hot).
__global__ __launch_bounds__(512, 4) void k_fused(const int* __restrict__ clist,
                                                  const float* __restrict__ edge,
                                                  float* __restrict__ wsf) {
  __shared__ __align__(16) unsigned short ebuf[2][MT * 64];  //  8192 B (XOR-swizzled)
  __shared__ float cls[2][2560];                             // 20480 B (A/B quarter slice)
  __shared__ int   rofsL[MT];

  const int* wsi = (const int*)wsf;
  const unsigned short* wtg = (const unsigned short*)(wsf + WS_WTG);
  int tid = threadIdx.x;
  int q = blockIdx.x & 3, mg = blockIdx.x >> 2;
  int count = wsi[WS_CNT];
  int p0 = mg * MT;
  if (p0 >= count) return;

  int qstart = q * QK;
  int qlen = (q == 3) ? (NV - 3 * QK) : QK;   // 2512 or 2496
  int nchunks = (qlen + 63) >> 6;             // 40 or 39

  // prologue: row bases + coefficient slice
  if (tid < MT) {
    int pos = p0 + tid;
    rofsL[tid] = (pos < count) ? clist[wsi[WS_ROWS + pos]] * NV : -1;
  }
  for (int i = tid; i < 640; i += 512) {
    int k = i * 4;
    float4 va = make_float4(0.f, 0.f, 0.f, 0.f), vb = va;
    if (k < qlen) {
      va = *(const float4*)&wsf[WS_A + qstart + k];
      vb = *(const float4*)&wsf[WS_B + qstart + k];
    }
    *(float4*)&cls[0][k] = va;
    *(float4*)&cls[1][k] = vb;
  }
  __syncthreads();

  int wv = tid >> 6, lane = tid & 63;
  int q4 = lane >> 4, l15 = lane & 15;
  int nt0 = (wv * NTI) >> 3, nt1 = ((wv + 1) * NTI) >> 3;   // 2-3 n-tiles/wave

  // staging slot: row rm_s (0..31), float4 col k4 (0..15); one slot/thread
  int rm_s = tid >> 4;
  int k4 = tid & 15;
  int rof = rofsL[rm_s];

  float4 eld; int vld = 0;
  float sAcc = 0.f;

  auto stage_load = [&](int tt, bool nv) {
    vld = 0;
    int koff = tt * 64 + k4 * 4;
    if (nv && rof >= 0 && koff < qlen) {
      eld = *(const float4*)(edge + (long)rof + qstart + koff);
      vld = 1;
    }
  };

  auto stage_write = [&](int buf, int tt) {
    int koff = tt * 64 + k4 * 4;
    int kc = (koff < qlen) ? koff : 0;
    float4 a = *(const float4*)&cls[0][kc];
    float4 b = *(const float4*)&cls[1][kc];
    float e0 = 0.f, e1 = 0.f, e2 = 0.f, e3 = 0.f;
    if (vld) {
      e0 = __expf(fmaf(a.x, eld.x, (eld.x > 0.f) ? b.x : 0.f));
      e1 = __expf(fmaf(a.y, eld.y, (eld.y > 0.f) ? b.y : 0.f));
      e2 = __expf(fmaf(a.z, eld.z, (eld.z > 0.f) ? b.z : 0.f));
      e3 = __expf(fmaf(a.w, eld.w, (eld.w > 0.f) ? b.w : 0.f));
      sAcc += e0 + e1 + e2 + e3;
    }
    ushort4 ev;
    ev.x = f2bf(e0); ev.y = f2bf(e1); ev.z = f2bf(e2); ev.w = f2bf(e3);
    int off = ((rm_s << 7) + (k4 << 3)) ^ ((rm_s & 7) << 4);
    *(ushort4*)((char*)&ebuf[buf][0] + off) = ev;
  };

  auto bload = [&](bf16x8 (&bf)[3][2], int tt) {
    #pragma unroll
    for (int j = 0; j < 3; ++j)
      #pragma unroll
      for (int c5 = 0; c5 < 2; ++c5)
        if (nt0 + j < nt1) {
          int n = (nt0 + j) * 16 + l15;
          bf[j][c5] = *(const bf16x8*)(const void*)
              &wtg[(long)n * WTGLD + qstart + tt * 64 + c5 * 32 + q4 * 8];
        }
  };

  f32x4 acc[2][3] = {};
  auto do_mfma = [&](int buf, const bf16x8 (&bf)[3][2]) {
    const char* eb = (const char*)&ebuf[buf][0];
    #pragma unroll
    for (int c5 = 0; c5 < 2; ++c5) {
      int kb2 = (c5 << 6) + (q4 << 4);
      int off0 = ((l15 << 7) + kb2) ^ ((l15 & 7) << 4);
      int off1 = (((16 + l15) << 7) + kb2) ^ ((l15 & 7) << 4);
      bf16x8 a0 = *(const bf16x8*)(const void*)(eb + off0);
      bf16x8 a1 = *(const bf16x8*)(const void*)(eb + off1);
      #pragma unroll
      for (int j = 0; j < 3; ++j) {
        if (nt0 + j < nt1) {
          acc[0][j] = __builtin_amdgcn_mfma_f32_16x16x32_bf16(a0, bf[j][c5], acc[0][j], 0, 0, 0);
          acc[1][j] = __builtin_amdgcn_mfma_f32_16x16x32_bf16(a1, bf[j][c5], acc[1][j], 0, 0, 0);
        }
      }
    }
  };

  // prologue: chunk 0 staged; bfragA = chunk 0
  bf16x8 bfragA[3][2] = {}, bfragB[3][2] = {};
  stage_load(0, true);
  bload(bfragA, 0);
  stage_write(0, 0);
  __syncthreads();

  for (int t = 0; t < nchunks; t += 2) {
    bool nv1 = (t + 1) < nchunks;
    // chunk t: ebuf0 + bfragA
    stage_load(t + 1, nv1);
    if (nv1) bload(bfragB, t + 1);
    do_mfma(0, bfragA);
    stage_write(1, t + 1);
    __syncthreads();
    if (nv1) {
      bool nv2 = (t + 2) < nchunks;
      // chunk t+1: ebuf1 + bfragB
      stage_load(t + 2, nv2);
      if (nv2) bload(bfragA, t + 2);
      do_mfma(1, bfragB);
      stage_write(0, t + 2);
      __syncthreads();
    }
  }

  // S_part: reduce over the 16 k4-lanes of each row (contiguous 16-lane groups)
  #pragma unroll
  for (int o = 1; o < 16; o <<= 1) sAcc += __shfl_xor(sAcc, o);
  if (k4 == 0) wsf[WS_SP + q * 8192 + p0 + rm_s] = sAcc;

  // U emit: unnormalized, exclusively owned -> plain stores
  float* Uq = wsf + WS_U + (long)q * UQSTRIDE;
  #pragma unroll
  for (int j = 0; j < 3; ++j) {
    if (nt0 + j < nt1) {
      int n = (nt0 + j) * 16 + l15;
      #pragma unroll
      for (int ms = 0; ms < 2; ++ms)
        #pragma unroll
        for (int r = 0; r < 4; ++r) {
          int m = ms * 16 + q4 * 4 + r;
          Uq[(long)(p0 + m) * 304 + n] = acc[ms][j][r];
        }
    }
  }
}

// normalize + batch-reduce: one block per batch, direct stores (no atomics)
__global__ __launch_bounds__(320) void k_norm(const float* __restrict__ wsf,
                                              float* __restrict__ out) {
  const int* wsi = (const int*)wsf;
  int b = blockIdx.x, n = threadIdx.x;
  if (n >= ND) return;
  int c0 = wsi[WS_CUM + b], c1 = wsi[WS_CUM + b + 1];
  float acc = 0.f;
  for (int pos = c0; pos < c1; ++pos) {
    float S = wsf[WS_SP + pos] + wsf[WS_SP + 8192 + pos] +
              wsf[WS_SP + 16384 + pos] + wsf[WS_SP + 24576 + pos];
    const float* Up = wsf + WS_U + (long)pos * 304 + n;
    float v = Up[0] + Up[UQSTRIDE] + Up[2L * UQSTRIDE] + Up[3L * UQSTRIDE];
    acc += v / S;
  }
  int len = c1 - c0;
  out[b * ND + n] = (len > 0) ? acc / (float)len : 0.f;
}

extern "C" void kernel_launch(void* const* d_in, const int* in_sizes, int n_in,
                              void* d_out, int out_size, void* d_ws, size_t ws_size,
                              hipStream_t stream) {
  const int*   clist = (const int*)d_in[0];
  const int*   clen  = (const int*)d_in[1];
  const float* embed = (const float*)d_in[2];
  const float* cw    = (const float*)d_in[3];
  const float* edge  = (const float*)d_in[4];
  const float* aff   = (const float*)d_in[5];
  const float* lam   = (const float*)d_in[6];
  float* out = (float*)d_out;
  float* wsf = (float*)d_ws;
  int*   wsi = (int*)d_ws;

  hipLaunchKernelGGL(k_init,    dim3(2),           dim3(256), 0, stream, wsf);
  hipLaunchKernelGGL(k_context, dim3(NB * CSL),    dim3(320), 0, stream, clist, clen, embed, wsf);
  hipLaunchKernelGGL(k_cn,      dim3(1),           dim3(320), 0, stream, wsf);
  hipLaunchKernelGGL(k_cos,     dim3(NV / 4),      dim3(256), 0, stream, cw, lam, aff, wsf);
  hipLaunchKernelGGL(k_wt,      dim3(WTGLD / 64),  dim3(256), 0, stream, cw, wsf);
  hipLaunchKernelGGL(k_compact, dim3(32),          dim3(256), 0, stream, clen, wsi);
  hipLaunchKernelGGL(k_fused,   dim3(MGMAX * 4),   dim3(512), 0, stream, clist, edge, wsf);
  hipLaunchKernelGGL(k_norm,    dim3(NB),          dim3(320), 0, stream, wsf, out);
}